// Round 8
// baseline (1160.614 us; speedup 1.0000x reference)
//
#include <hip/hip_runtime.h>
#include <hip/hip_bf16.h>
#include <math.h>

// Problem dims
#define VV   32000
#define DIM  256
#define BB   4
#define SS   512
#define TT   256
#define D2   512
#define D3   768

typedef __attribute__((ext_vector_type(8))) short s16x8;
typedef __attribute__((ext_vector_type(4))) float f32x4;

__device__ __forceinline__ float rcp_(float x) { return __builtin_amdgcn_rcpf(x); }
// fast sigmoid/tanh: v_rcp_f32 (1 ulp) instead of full-precision division.
// The old 1/(1+e) and (e2-1)/(e2+1) forms each lowered to the ~15-instr
// v_div_scale/div_fmas/div_fixup sequence - 6 of them per thread-step made
// VALUBusy~0.43 co-critical with MFMA (R7 counters).
__device__ __forceinline__ float sigmoidf_(float x) { return rcp_(1.0f + __expf(-x)); }
__device__ __forceinline__ float tanhf_(float x) {
    float t = __expf(-2.0f * x);
    return (1.0f - t) * rcp_(1.0f + t);
}
__device__ __forceinline__ short f2bf(float f) {  // RNE f32->bf16
    unsigned u = __float_as_uint(f);
    u += 0x7FFFu + ((u >> 16) & 1u);
    return (short)(u >> 16);
}

// R4-proven barrier: one asm unit (waitcnt+barrier), memory clobber. lgkm-only
// drain keeps global loads/stores in flight across the barrier.
#define BAR_LGKM() asm volatile("s_waitcnt lgkmcnt(0)\n\ts_barrier" ::: "memory")

// ---------------------------------------------------------------------------
// Embedding + positional add for src and tgt
// ---------------------------------------------------------------------------
__global__ __launch_bounds__(256) void k_embed(const int* __restrict__ src,
                                               const int* __restrict__ tgt,
                                               const float* __restrict__ emb,
                                               const float* __restrict__ pos,
                                               float* __restrict__ src_emb,
                                               float* __restrict__ tgt_emb) {
    int i = blockIdx.x * 256 + threadIdx.x;
    const int nS = BB * SS * DIM;
    if (i < nS) {
        int d = i & (DIM - 1);
        int s = (i >> 8) & (SS - 1);
        int b = i >> 17;
        src_emb[i] = emb[(size_t)src[b * SS + s] * DIM + d] + pos[s * DIM + d];
    } else {
        int j = i - nS;
        int d = j & (DIM - 1);
        int t = (j >> 8) & (TT - 1);
        int b = j >> 16;
        tgt_emb[j] = emb[(size_t)tgt[b * TT + t] * DIM + d] + pos[t * DIM + d];
    }
}

// ---------------------------------------------------------------------------
// Batched small f32 GEMM: up to 3 descs, blockIdx.z selects.
// ---------------------------------------------------------------------------
struct GDesc {
    const float* A; int lda;
    const float* Bt; int ldb;
    const float* bias;
    float* C; int ldc;
    int M, N;
};

#define BMM 128
#define BNN 128
#define BKK 8

__global__ __launch_bounds__(256) void k_gemmb(GDesc d0, GDesc d1, GDesc d2) {
    GDesc d = (blockIdx.z == 0) ? d0 : ((blockIdx.z == 1) ? d1 : d2);
    int brow = blockIdx.y * BMM, bcol = blockIdx.x * BNN;
    if (brow >= d.M || bcol >= d.N) return;

    __shared__ float As[BKK][BMM + 4];
    __shared__ float Bs[BKK][BNN + 4];
    const int K = d.lda;
    int tid = threadIdx.x;
    int tx = tid & 15, ty = tid >> 4;
    float acc[8][8];
#pragma unroll
    for (int i = 0; i < 8; i++)
#pragma unroll
        for (int j = 0; j < 8; j++) acc[i][j] = 0.0f;

    int lr = tid >> 1;
    int lk = (tid & 1) * 4;
    for (int k0 = 0; k0 < K; k0 += BKK) {
        float4 a4 = *(const float4*)&d.A[(size_t)(brow + lr) * d.lda + k0 + lk];
        float4 b4 = *(const float4*)&d.Bt[(size_t)(bcol + lr) * d.ldb + k0 + lk];
        As[lk + 0][lr] = a4.x; As[lk + 1][lr] = a4.y; As[lk + 2][lr] = a4.z; As[lk + 3][lr] = a4.w;
        Bs[lk + 0][lr] = b4.x; Bs[lk + 1][lr] = b4.y; Bs[lk + 2][lr] = b4.z; Bs[lk + 3][lr] = b4.w;
        __syncthreads();
#pragma unroll
        for (int kk = 0; kk < BKK; kk++) {
            float4 a0 = *(const float4*)&As[kk][ty * 8];
            float4 a1 = *(const float4*)&As[kk][ty * 8 + 4];
            float4 b0 = *(const float4*)&Bs[kk][tx * 8];
            float4 b1 = *(const float4*)&Bs[kk][tx * 8 + 4];
            float av[8] = {a0.x, a0.y, a0.z, a0.w, a1.x, a1.y, a1.z, a1.w};
            float bv[8] = {b0.x, b0.y, b0.z, b0.w, b1.x, b1.y, b1.z, b1.w};
#pragma unroll
            for (int i = 0; i < 8; i++)
#pragma unroll
                for (int j = 0; j < 8; j++) acc[i][j] += av[i] * bv[j];
        }
        __syncthreads();
    }

    float bv0[8];
#pragma unroll
    for (int j = 0; j < 8; j++) bv0[j] = d.bias ? d.bias[bcol + tx * 8 + j] : 0.0f;

#pragma unroll
    for (int i = 0; i < 8; i++) {
        size_t row = brow + ty * 8 + i;
        float4 c0 = make_float4(acc[i][0] + bv0[0], acc[i][1] + bv0[1],
                                acc[i][2] + bv0[2], acc[i][3] + bv0[3]);
        float4 c1 = make_float4(acc[i][4] + bv0[4], acc[i][5] + bv0[5],
                                acc[i][6] + bv0[6], acc[i][7] + bv0[7]);
        *(float4*)&d.C[row * d.ldc + bcol + tx * 8] = c0;
        *(float4*)&d.C[row * d.ldc + bcol + tx * 8 + 4] = c1;
    }
}

// ---------------------------------------------------------------------------
// GRU recurrences, persistent-register-weight MFMA.
// Round-8: R6 interleaved MFMA loop (R7 split reverted) + fast-math epilogue.
// ---------------------------------------------------------------------------
#define HSTRIDE 576
#define HBUF    (4 * HSTRIDE)   // 2304 B per buffer

__global__ __launch_bounds__(512, 2) void k_gru(const float* __restrict__ ef_x,
                                                const float* __restrict__ eb_x,
                                                const float* __restrict__ d_x,
                                                const float* __restrict__ ef_whh, const float* __restrict__ ef_bhh,
                                                const float* __restrict__ eb_whh, const float* __restrict__ eb_bhh,
                                                const float* __restrict__ d_whh, const float* __restrict__ d_bhh,
                                                float* __restrict__ enc_out,
                                                float* __restrict__ dec_out) {
    __shared__ __align__(16) char hb[2 * HBUF];  // double-buffered h (bf16)

    int tid = threadIdx.x;
    int dir = blockIdx.x;
    const float *xw, *Whh, *bhh;
    int L;
    if (dir == 0)      { xw = ef_x; Whh = ef_whh; bhh = ef_bhh; L = SS; }
    else if (dir == 1) { xw = eb_x; Whh = eb_whh; bhh = eb_bhh; L = SS; }
    else               { xw = d_x;  Whh = d_whh;  bhh = d_bhh;  L = TT; }

    const int wv = tid >> 6;
    const int lane = tid & 63;
    const int jj = lane & 15;
    const int hi = lane >> 4;
    const int b = hi;

    // zero both h buffers
    if (tid < 288) {
        f32x4 z = {0.f, 0.f, 0.f, 0.f};
        *(f32x4*)(hb + tid * 16) = z;
    }

    // persistent B-fragments wf[gate][tile][kslice]
    s16x8 wf[3][2][8];
#pragma unroll
    for (int g = 0; g < 3; ++g)
#pragma unroll
        for (int t = 0; t < 2; ++t) {
            const int nrow = g * 256 + wv * 32 + t * 16 + jj;
            const float* wp = Whh + (size_t)nrow * 256 + hi * 8;
#pragma unroll
            for (int sk = 0; sk < 8; ++sk) {
                float4 w0 = *(const float4*)(wp + sk * 32);
                float4 w1 = *(const float4*)(wp + sk * 32 + 4);
                s16x8 v;
                v[0] = f2bf(w0.x); v[1] = f2bf(w0.y); v[2] = f2bf(w0.z); v[3] = f2bf(w0.w);
                v[4] = f2bf(w1.x); v[5] = f2bf(w1.y); v[6] = f2bf(w1.z); v[7] = f2bf(w1.w);
                wf[g][t][sk] = v;
            }
        }

    const int j0 = wv * 32 + jj, j1 = j0 + 16;
    const float br0 = bhh[j0], bz0 = bhh[256 + j0], bn0 = bhh[512 + j0];
    const float br1 = bhh[j1], bz1 = bhh[256 + j1], bn1 = bhh[512 + j1];

    const int arow = jj >> 2;
    const int abase = arow * HSTRIDE + hi * 16;
    const int wo0 = b * HSTRIDE + 2 * j0;
    const int wo1 = b * HSTRIDE + 2 * j1;

    const int s0 = (dir == 1) ? (L - 1) : 0;
    const int sst = (dir == 1) ? -1 : 1;
    const float* xq = xw + ((size_t)b * L + s0) * D3 + j0;
    float* op;
    int ostride;
    if (dir == 2) { op = dec_out + ((size_t)b * TT + s0) * DIM + j0; ostride = sst * DIM; }
    else          { op = enc_out + ((size_t)b * SS + s0) * D2 + (dir == 1 ? DIM : 0) + j0; ostride = sst * D2; }
    const int xstride = sst * D3;

    // prefetch step-0 x gates
    float c0 = xq[0], c1 = xq[256], c2 = xq[512], c3 = xq[16], c4 = xq[272], c5 = xq[528];

    float h0 = 0.f, h1 = 0.f;
    int cur = 0;
    __syncthreads();

    for (int st = 0; st < L; ++st) {
        // next step's x loads: in flight across the lgkm-only barrier
        xq += xstride;
        float n0 = xq[0], n1 = xq[256], n2 = xq[512], n3 = xq[16], n4 = xq[272], n5 = xq[528];

        const char* hcur = hb + cur * HBUF;
        f32x4 a00 = {0.f, 0.f, 0.f, 0.f}, a01 = a00, a10 = a00, a11 = a00, a20 = a00, a21 = a00;
#pragma unroll
        for (int sk = 0; sk < 8; ++sk) {
            s16x8 af = *(const s16x8*)(hcur + abase + 64 * sk);
            a00 = __builtin_amdgcn_mfma_f32_16x16x32_bf16(af, wf[0][0][sk], a00, 0, 0, 0);
            a01 = __builtin_amdgcn_mfma_f32_16x16x32_bf16(af, wf[0][1][sk], a01, 0, 0, 0);
            a10 = __builtin_amdgcn_mfma_f32_16x16x32_bf16(af, wf[1][0][sk], a10, 0, 0, 0);
            a11 = __builtin_amdgcn_mfma_f32_16x16x32_bf16(af, wf[1][1][sk], a11, 0, 0, 0);
            a20 = __builtin_amdgcn_mfma_f32_16x16x32_bf16(af, wf[2][0][sk], a20, 0, 0, 0);
            a21 = __builtin_amdgcn_mfma_f32_16x16x32_bf16(af, wf[2][1][sk], a21, 0, 0, 0);
        }

        float r0 = sigmoidf_(c0 + a00[0] + br0);
        float z0 = sigmoidf_(c1 + a10[0] + bz0);
        float nn0 = tanhf_(c2 + r0 * (a20[0] + bn0));
        h0 = (1.f - z0) * nn0 + z0 * h0;
        float r1 = sigmoidf_(c3 + a01[0] + br1);
        float z1 = sigmoidf_(c4 + a11[0] + bz1);
        float nn1 = tanhf_(c5 + r1 * (a21[0] + bn1));
        h1 = (1.f - z1) * nn1 + z1 * h1;

        char* hnxt = hb + (cur ^ 1) * HBUF;
        *(short*)(hnxt + wo0) = f2bf(h0);
        *(short*)(hnxt + wo1) = f2bf(h1);
        op[0] = h0;   // global store: never drained in-loop
        op[16] = h1;
        BAR_LGKM();   // lgkm-only drain + barrier

        cur ^= 1;
        c0 = n0; c1 = n1; c2 = n2; c3 = n3; c4 = n4; c5 = n5;
        op += ostride;
    }
}

// ---------------------------------------------------------------------------
// Attention: one block per (b,t) row, 512 threads.
// ---------------------------------------------------------------------------
__global__ __launch_bounds__(512) void k_attn(const float* __restrict__ Qb,
                                              const float* __restrict__ Kb,
                                              const float* __restrict__ enc_out,
                                              const float* __restrict__ dec_out,
                                              const float* __restrict__ Wgate,
                                              const float* __restrict__ bgate,
                                              float* __restrict__ probs,
                                              short* __restrict__ cmb,
                                              float* __restrict__ gate) {
    __shared__ float q[DIM];
    __shared__ float sc[SS];
    __shared__ float red[512];
    __shared__ float par[2][2][DIM];
    int row = blockIdx.x;
    int b = row >> 8;
    int tid = threadIdx.x;

    if (tid < DIM) q[tid] = Qb[(size_t)row * DIM + tid];
    __syncthreads();

    const float scale = 0.0625f;  // 1/sqrt(256)
    {
        const float* kr = Kb + ((size_t)b * SS + tid) * DIM;
        float acc = 0.0f;
        for (int k = 0; k < DIM; k += 4) {
            float4 k4 = *(const float4*)&kr[k];
            acc += k4.x * q[k] + k4.y * q[k + 1] + k4.z * q[k + 2] + k4.w * q[k + 3];
        }
        sc[tid] = acc * scale;
    }
    __syncthreads();

    red[tid] = sc[tid];
    __syncthreads();
    for (int o = 256; o > 0; o >>= 1) {
        if (tid < o) red[tid] = fmaxf(red[tid], red[tid + o]);
        __syncthreads();
    }
    float m = red[0];
    __syncthreads();

    float e0 = __expf(sc[tid] - m);
    sc[tid] = e0;
    red[tid] = e0;
    __syncthreads();
    for (int o = 256; o > 0; o >>= 1) {
        if (tid < o) red[tid] += red[tid + o];
        __syncthreads();
    }
    float inv = rcp_(red[0]);
    __syncthreads();

    sc[tid] *= inv;
    probs[(size_t)row * SS + tid] = sc[tid];
    __syncthreads();

    // context, s split across halves
    {
        int d = tid & 255, sh = tid >> 8;
        float accf = 0.0f, accb = 0.0f;
        const float* ep = enc_out + ((size_t)b * SS + sh * 256) * D2 + d;
        const float* pp = &sc[sh * 256];
        for (int s = 0; s < 256; s++) {
            float p = pp[s];
            accf += p * ep[(size_t)s * D2];
            accb += p * ep[(size_t)s * D2 + DIM];
        }
        par[sh][0][d] = accf;
        par[sh][1][d] = accb;
    }
    __syncthreads();

    if (tid < DIM) {
        float af = par[0][0][tid] + par[1][0][tid];
        float ab = par[0][1][tid] + par[1][1][tid];
        float dv = dec_out[(size_t)row * DIM + tid];
        cmb[(size_t)row * D3 + tid] = f2bf(dv);
        cmb[(size_t)row * D3 + DIM + tid] = f2bf(af);
        cmb[(size_t)row * D3 + 2 * DIM + tid] = f2bf(ab);
        red[tid] = dv * Wgate[tid] + af * Wgate[DIM + tid] + ab * Wgate[2 * DIM + tid];
    }
    __syncthreads();
    for (int o = 128; o > 0; o >>= 1) {
        if (tid < o) red[tid] += red[tid + o];
        __syncthreads();
    }
    if (tid == 0) gate[row] = sigmoidf_(red[0] + bgate[0]);
}

// ---------------------------------------------------------------------------
// Generator logits GEMM (bf16 MFMA) + fused per-row sum(exp(logit)).
// ---------------------------------------------------------------------------
__global__ __launch_bounds__(512) void k_gen(const short* __restrict__ A,
                                             const float* __restrict__ Bw,
                                             const float* __restrict__ bias,
                                             float* __restrict__ C,
                                             float* __restrict__ rowsum) {
    __shared__ __align__(16) short As[256 * 32];
    __shared__ __align__(16) short Bs[128 * 32];
    int tid = threadIdx.x;
    int lane = tid & 63, wv = tid >> 6;
    int wm = wv >> 1, wn = wv & 1;
    int brow = blockIdx.y * 256, bcol = blockIdx.x * 128;
    f32x4 acc[4][4];
#pragma unroll
    for (int i = 0; i < 4; i++)
#pragma unroll
        for (int j = 0; j < 4; j++) acc[i][j] = (f32x4){0.f, 0.f, 0.f, 0.f};

    const int ca0 = tid, ca1 = tid + 512, cb = tid;
    const int ll = lane & 15, lh = lane >> 4;

    for (int k0 = 0; k0 < D3; k0 += 32) {
        s16x8 va0 = *(const s16x8*)&A[(size_t)(brow + (ca0 >> 2)) * D3 + k0 + (ca0 & 3) * 8];
        s16x8 va1 = *(const s16x8*)&A[(size_t)(brow + (ca1 >> 2)) * D3 + k0 + (ca1 & 3) * 8];
        const float* bp = &Bw[(size_t)(bcol + (cb >> 2)) * D3 + k0 + (cb & 3) * 8];
        float4 b0 = *(const float4*)bp;
        float4 b1 = *(const float4*)(bp + 4);
        s16x8 vb;
        vb[0] = f2bf(b0.x); vb[1] = f2bf(b0.y); vb[2] = f2bf(b0.z); vb[3] = f2bf(b0.w);
        vb[4] = f2bf(b1.x); vb[5] = f2bf(b1.y); vb[6] = f2bf(b1.z); vb[7] = f2bf(b1.w);

        __syncthreads();
        *(s16x8*)&As[ca0 * 8] = va0;
        *(s16x8*)&As[ca1 * 8] = va1;
        *(s16x8*)&Bs[cb * 8] = vb;
        __syncthreads();

        s16x8 af[4], bf[4];
#pragma unroll
        for (int mt = 0; mt < 4; ++mt)
            af[mt] = *(const s16x8*)&As[(wm * 64 + mt * 16 + ll) * 32 + lh * 8];
#pragma unroll
        for (int nt = 0; nt < 4; ++nt)
            bf[nt] = *(const s16x8*)&Bs[(wn * 64 + nt * 16 + ll) * 32 + lh * 8];
#pragma unroll
        for (int mt = 0; mt < 4; ++mt)
#pragma unroll
            for (int nt = 0; nt < 4; ++nt)
                acc[mt][nt] = __builtin_amdgcn_mfma_f32_16x16x32_bf16(af[mt], bf[nt], acc[mt][nt], 0, 0, 0);
    }

#pragma unroll
    for (int nt = 0; nt < 4; ++nt) {
        float bv = bias[bcol + wn * 64 + nt * 16 + ll];
#pragma unroll
        for (int mt = 0; mt < 4; ++mt)
#pragma unroll
            for (int q = 0; q < 4; ++q) acc[mt][nt][q] += bv;
    }

#pragma unroll
    for (int mt = 0; mt < 4; ++mt) {
        int row = brow + wm * 64 + mt * 16 + lh * 4;
#pragma unroll
        for (int nt = 0; nt < 4; ++nt) {
            int col = bcol + wn * 64 + nt * 16 + ll;
#pragma unroll
            for (int q = 0; q < 4; ++q)
                C[(size_t)(row + q) * VV + col] = acc[mt][nt][q];
        }
    }

#pragma unroll
    for (int mt = 0; mt < 4; ++mt) {
#pragma unroll
        for (int q = 0; q < 4; ++q) {
            float se = __expf(acc[mt][0][q]) + __expf(acc[mt][1][q]) +
                       __expf(acc[mt][2][q]) + __expf(acc[mt][3][q]);
#pragma unroll
            for (int off = 1; off < 16; off <<= 1)
                se += __shfl_xor(se, off);
            if (ll == 0) {
                int row = brow + wm * 64 + mt * 16 + lh * 4 + q;
                atomicAdd(&rowsum[row], se);
            }
        }
    }
}

// ---------------------------------------------------------------------------
// Fused normalize + copy-scatter: one block per row.
// ---------------------------------------------------------------------------
__global__ __launch_bounds__(256) void k_finsc(const int* __restrict__ src,
                                               const float* __restrict__ probs,
                                               const float* __restrict__ gate,
                                               const float* __restrict__ rowsum,
                                               float* __restrict__ out) {
    int row = blockIdx.x;     // b*TT + t
    int b = row >> 8;
    int tid = threadIdx.x;
    float g = gate[row];
    float inv = g / rowsum[row];
    float* op = out + (size_t)row * VV;

    for (int i = tid; i < VV / 4; i += 256) {
        float4 l = *(const float4*)&op[i * 4];
        l.x = __expf(l.x) * inv;
        l.y = __expf(l.y) * inv;
        l.z = __expf(l.z) * inv;
        l.w = __expf(l.w) * inv;
        *(float4*)&op[i * 4] = l;
    }
    __syncthreads();  // drains vmcnt: normalize writes complete before scatter

    float og = 1.0f - g;
#pragma unroll
    for (int h = 0; h < 2; ++h) {
        int s = tid + h * 256;
        float val = og * probs[(size_t)row * SS + s];
        atomicAdd(&op[src[b * SS + s]], val);
    }
}

// ---------------------------------------------------------------------------
extern "C" void kernel_launch(void* const* d_in, const int* in_sizes, int n_in,
                              void* d_out, int out_size, void* d_ws, size_t ws_size,
                              hipStream_t stream) {
    const int*   src    = (const int*)d_in[0];
    const int*   tgt    = (const int*)d_in[1];
    const float* emb    = (const float*)d_in[2];
    const float* pos    = (const float*)d_in[3];
    const float* ef_wih = (const float*)d_in[4];
    const float* ef_whh = (const float*)d_in[5];
    const float* ef_bih = (const float*)d_in[6];
    const float* ef_bhh = (const float*)d_in[7];
    const float* eb_wih = (const float*)d_in[8];
    const float* eb_whh = (const float*)d_in[9];
    const float* eb_bih = (const float*)d_in[10];
    const float* eb_bhh = (const float*)d_in[11];
    const float* d_wih  = (const float*)d_in[12];
    const float* d_whh  = (const float*)d_in[13];
    const float* d_bih  = (const float*)d_in[14];
    const float* d_bhh  = (const float*)d_in[15];
    const float* Wq     = (const float*)d_in[16];
    const float* Wk     = (const float*)d_in[17];
    const float* Wgen   = (const float*)d_in[18];
    const float* bgen   = (const float*)d_in[19];
    const float* Wgate  = (const float*)d_in[20];
    const float* bgate  = (const float*)d_in[21];
    float* out = (float*)d_out;
    float* ws  = (float*)d_ws;

    float* src_emb  = ws;
    float* tgt_emb  = src_emb + (size_t)BB * SS * DIM;
    float* ef_x     = tgt_emb + (size_t)BB * TT * DIM;
    float* eb_x     = ef_x + (size_t)BB * SS * D3;
    float* d_x      = eb_x + (size_t)BB * SS * D3;
    float* enc_out  = d_x + (size_t)BB * TT * D3;
    float* dec_out  = enc_out + (size_t)BB * SS * D2;
    float* Qb       = dec_out + (size_t)BB * TT * DIM;
    float* Kb       = Qb + (size_t)BB * TT * DIM;
    float* probs    = Kb + (size_t)BB * SS * DIM;
    short* cmb_bf   = (short*)(probs + (size_t)BB * TT * SS);
    float* gate     = (float*)(cmb_bf + (size_t)BB * TT * D3);
    float* rowsum   = gate + 1024;

    hipMemsetAsync(rowsum, 0, 1024 * sizeof(float), stream);

    // 1. embeddings
    k_embed<<<(BB * SS * DIM + BB * TT * DIM) / 256, 256, 0, stream>>>(
        src, tgt, emb, pos, src_emb, tgt_emb);

    // 2. input projections (batched)
    {
        GDesc e0 = {src_emb, DIM, ef_wih, DIM, ef_bih, ef_x, D3, BB * SS, D3};
        GDesc e1 = {src_emb, DIM, eb_wih, DIM, eb_bih, eb_x, D3, BB * SS, D3};
        GDesc e2 = {tgt_emb, DIM, d_wih, DIM, d_bih, d_x, D3, BB * TT, D3};
        k_gemmb<<<dim3(D3 / BNN, BB * SS / BMM, 3), 256, 0, stream>>>(e0, e1, e2);
    }

    // 3. the three recurrences
    k_gru<<<3, 512, 0, stream>>>(ef_x, eb_x, d_x, ef_whh, ef_bhh, eb_whh, eb_bhh,
                                 d_whh, d_bhh, enc_out, dec_out);

    // 4. Q/K projections (batched)
    {
        GDesc q0 = {dec_out, DIM, Wq, DIM, nullptr, Qb, DIM, BB * TT, DIM};
        GDesc q1 = {enc_out, D2, Wk, D2, nullptr, Kb, DIM, BB * SS, DIM};
        k_gemmb<<<dim3(DIM / BNN, BB * SS / BMM, 2), 256, 0, stream>>>(q0, q1, q1);
    }

    // 5. attention + combined(bf16) + gate
    k_attn<<<BB * TT, 512, 0, stream>>>(Qb, Kb, enc_out, dec_out, Wgate, bgate,
                                        probs, cmb_bf, gate);

    // 6. generator logits + fused rowsum
    k_gen<<<dim3(VV / 128, (BB * TT) / 256), 512, 0, stream>>>(cmb_bf, Wgen, bgen, out, rowsum);

    // 7. fused normalize + copy-scatter (one block per row)
    k_finsc<<<BB * TT, 256, 0, stream>>>(src, probs, gate, rowsum, out);
}

// Round 9
// 1142.249 us; speedup vs baseline: 1.0161x; 1.0161x over previous
//
#include <hip/hip_runtime.h>
#include <hip/hip_bf16.h>
#include <math.h>

// Problem dims
#define VV   32000
#define DIM  256
#define BB   4
#define SS   512
#define TT   256
#define D2   512
#define D3   768

typedef __attribute__((ext_vector_type(8))) short s16x8;
typedef __attribute__((ext_vector_type(4))) float f32x4;

__device__ __forceinline__ float rcp_(float x) { return __builtin_amdgcn_rcpf(x); }
__device__ __forceinline__ float sigmoidf_(float x) { return rcp_(1.0f + __expf(-x)); }
__device__ __forceinline__ float tanhf_(float x) {
    float t = __expf(-2.0f * x);
    return (1.0f - t) * rcp_(1.0f + t);
}
__device__ __forceinline__ short f2bf(float f) {  // RNE f32->bf16
    unsigned u = __float_as_uint(f);
    u += 0x7FFFu + ((u >> 16) & 1u);
    return (short)(u >> 16);
}

// R4-proven barrier: lgkm-only drain keeps global loads/stores in flight.
#define BAR_LGKM() asm volatile("s_waitcnt lgkmcnt(0)\n\ts_barrier" ::: "memory")

// ---------------------------------------------------------------------------
// Embedding + positional add for src and tgt
// ---------------------------------------------------------------------------
__global__ __launch_bounds__(256) void k_embed(const int* __restrict__ src,
                                               const int* __restrict__ tgt,
                                               const float* __restrict__ emb,
                                               const float* __restrict__ pos,
                                               float* __restrict__ src_emb,
                                               float* __restrict__ tgt_emb) {
    int i = blockIdx.x * 256 + threadIdx.x;
    const int nS = BB * SS * DIM;
    if (i < nS) {
        int d = i & (DIM - 1);
        int s = (i >> 8) & (SS - 1);
        int b = i >> 17;
        src_emb[i] = emb[(size_t)src[b * SS + s] * DIM + d] + pos[s * DIM + d];
    } else {
        int j = i - nS;
        int d = j & (DIM - 1);
        int t = (j >> 8) & (TT - 1);
        int b = j >> 16;
        tgt_emb[j] = emb[(size_t)tgt[b * TT + t] * DIM + d] + pos[t * DIM + d];
    }
}

// ---------------------------------------------------------------------------
// f32 -> bf16 bulk convert (Wgen pre-pass; result is L3-resident at 49MB)
// ---------------------------------------------------------------------------
__global__ __launch_bounds__(256) void k_cvt(const float* __restrict__ in,
                                             short* __restrict__ outp, int n8) {
    int i = blockIdx.x * 256 + threadIdx.x;
    if (i >= n8) return;
    const float4* p = (const float4*)(in + (size_t)i * 8);
    float4 a = p[0], b = p[1];
    s16x8 v;
    v[0] = f2bf(a.x); v[1] = f2bf(a.y); v[2] = f2bf(a.z); v[3] = f2bf(a.w);
    v[4] = f2bf(b.x); v[5] = f2bf(b.y); v[6] = f2bf(b.z); v[7] = f2bf(b.w);
    *(s16x8*)(outp + (size_t)i * 8) = v;
}

// ---------------------------------------------------------------------------
// Batched small f32 GEMM (Q/K projections): blockIdx.z selects desc.
// ---------------------------------------------------------------------------
struct GDesc {
    const float* A; int lda;
    const float* Bt; int ldb;
    const float* bias;
    float* C; int ldc;
    int M, N;
};

#define BMM 128
#define BNN 128
#define BKK 8

__global__ __launch_bounds__(256) void k_gemmb(GDesc d0, GDesc d1, GDesc d2) {
    GDesc d = (blockIdx.z == 0) ? d0 : ((blockIdx.z == 1) ? d1 : d2);
    int brow = blockIdx.y * BMM, bcol = blockIdx.x * BNN;
    if (brow >= d.M || bcol >= d.N) return;

    __shared__ float As[BKK][BMM + 4];
    __shared__ float Bs[BKK][BNN + 4];
    const int K = d.lda;
    int tid = threadIdx.x;
    int tx = tid & 15, ty = tid >> 4;
    float acc[8][8];
#pragma unroll
    for (int i = 0; i < 8; i++)
#pragma unroll
        for (int j = 0; j < 8; j++) acc[i][j] = 0.0f;

    int lr = tid >> 1;
    int lk = (tid & 1) * 4;
    for (int k0 = 0; k0 < K; k0 += BKK) {
        float4 a4 = *(const float4*)&d.A[(size_t)(brow + lr) * d.lda + k0 + lk];
        float4 b4 = *(const float4*)&d.Bt[(size_t)(bcol + lr) * d.ldb + k0 + lk];
        As[lk + 0][lr] = a4.x; As[lk + 1][lr] = a4.y; As[lk + 2][lr] = a4.z; As[lk + 3][lr] = a4.w;
        Bs[lk + 0][lr] = b4.x; Bs[lk + 1][lr] = b4.y; Bs[lk + 2][lr] = b4.z; Bs[lk + 3][lr] = b4.w;
        __syncthreads();
#pragma unroll
        for (int kk = 0; kk < BKK; kk++) {
            float4 a0 = *(const float4*)&As[kk][ty * 8];
            float4 a1 = *(const float4*)&As[kk][ty * 8 + 4];
            float4 b0 = *(const float4*)&Bs[kk][tx * 8];
            float4 b1 = *(const float4*)&Bs[kk][tx * 8 + 4];
            float av[8] = {a0.x, a0.y, a0.z, a0.w, a1.x, a1.y, a1.z, a1.w};
            float bv[8] = {b0.x, b0.y, b0.z, b0.w, b1.x, b1.y, b1.z, b1.w};
#pragma unroll
            for (int i = 0; i < 8; i++)
#pragma unroll
                for (int j = 0; j < 8; j++) acc[i][j] += av[i] * bv[j];
        }
        __syncthreads();
    }

    float bv0[8];
#pragma unroll
    for (int j = 0; j < 8; j++) bv0[j] = d.bias ? d.bias[bcol + tx * 8 + j] : 0.0f;

#pragma unroll
    for (int i = 0; i < 8; i++) {
        size_t row = brow + ty * 8 + i;
        float4 c0 = make_float4(acc[i][0] + bv0[0], acc[i][1] + bv0[1],
                                acc[i][2] + bv0[2], acc[i][3] + bv0[3]);
        float4 c1 = make_float4(acc[i][4] + bv0[4], acc[i][5] + bv0[5],
                                acc[i][6] + bv0[6], acc[i][7] + bv0[7]);
        *(float4*)&d.C[row * d.ldc + bcol + tx * 8] = c0;
        *(float4*)&d.C[row * d.ldc + bcol + tx * 8 + 4] = c1;
    }
}

// ---------------------------------------------------------------------------
// Input projections as bf16 MFMA: C[M,768] = A[M,256] @ W[768,256]^T + bias.
// A,W are f32, converted to bf16 in the staging path. Tile 256x128, BK=32,
// 512 threads (8 waves, 4Mx2N). Same MFMA structure as k_gen (HW-verified).
// ---------------------------------------------------------------------------
struct PDesc {
    const float* A;
    const float* Bt;
    const float* bias;
    float* C;
    int M;
};

__global__ __launch_bounds__(512) void k_proj(PDesc p0, PDesc p1, PDesc p2) {
    PDesc p = (blockIdx.z == 0) ? p0 : ((blockIdx.z == 1) ? p1 : p2);
    int brow = blockIdx.y * 256;
    if (brow >= p.M) return;
    int bcol = blockIdx.x * 128;

    __shared__ __align__(16) short As[256 * 32];
    __shared__ __align__(16) short Bs[128 * 32];
    int tid = threadIdx.x;
    int lane = tid & 63, wv = tid >> 6;
    int wm = wv >> 1, wn = wv & 1;
    const int ll = lane & 15, lh = lane >> 4;

    f32x4 acc[4][4];
#pragma unroll
    for (int i = 0; i < 4; i++)
#pragma unroll
        for (int j = 0; j < 4; j++) acc[i][j] = (f32x4){0.f, 0.f, 0.f, 0.f};

    // A: 256 rows x 32 k per iter, thread covers row=tid>>1, 16 f32 at (tid&1)*16
    const int ar = tid >> 1, ak = (tid & 1) * 16;
    // B: 128 rows x 32 k, thread covers row=tid>>2, 8 f32 at (tid&3)*8
    const int br = tid >> 2, bk = (tid & 3) * 8;

    for (int k0 = 0; k0 < DIM; k0 += 32) {
        const float* ap = &p.A[(size_t)(brow + ar) * DIM + k0 + ak];
        float4 a0 = *(const float4*)ap;
        float4 a1 = *(const float4*)(ap + 4);
        float4 a2 = *(const float4*)(ap + 8);
        float4 a3 = *(const float4*)(ap + 12);
        const float* bp = &p.Bt[(size_t)(bcol + br) * DIM + k0 + bk];
        float4 b0 = *(const float4*)bp;
        float4 b1 = *(const float4*)(bp + 4);
        s16x8 va0, va1, vb;
        va0[0] = f2bf(a0.x); va0[1] = f2bf(a0.y); va0[2] = f2bf(a0.z); va0[3] = f2bf(a0.w);
        va0[4] = f2bf(a1.x); va0[5] = f2bf(a1.y); va0[6] = f2bf(a1.z); va0[7] = f2bf(a1.w);
        va1[0] = f2bf(a2.x); va1[1] = f2bf(a2.y); va1[2] = f2bf(a2.z); va1[3] = f2bf(a2.w);
        va1[4] = f2bf(a3.x); va1[5] = f2bf(a3.y); va1[6] = f2bf(a3.z); va1[7] = f2bf(a3.w);
        vb[0] = f2bf(b0.x); vb[1] = f2bf(b0.y); vb[2] = f2bf(b0.z); vb[3] = f2bf(b0.w);
        vb[4] = f2bf(b1.x); vb[5] = f2bf(b1.y); vb[6] = f2bf(b1.z); vb[7] = f2bf(b1.w);

        __syncthreads();
        *(s16x8*)&As[ar * 32 + ak] = va0;
        *(s16x8*)&As[ar * 32 + ak + 8] = va1;
        *(s16x8*)&Bs[br * 32 + bk] = vb;
        __syncthreads();

        s16x8 af[4], bf[4];
#pragma unroll
        for (int mt = 0; mt < 4; ++mt)
            af[mt] = *(const s16x8*)&As[(wm * 64 + mt * 16 + ll) * 32 + lh * 8];
#pragma unroll
        for (int nt = 0; nt < 4; ++nt)
            bf[nt] = *(const s16x8*)&Bs[(wn * 64 + nt * 16 + ll) * 32 + lh * 8];
#pragma unroll
        for (int mt = 0; mt < 4; ++mt)
#pragma unroll
            for (int nt = 0; nt < 4; ++nt)
                acc[mt][nt] = __builtin_amdgcn_mfma_f32_16x16x32_bf16(af[mt], bf[nt], acc[mt][nt], 0, 0, 0);
    }

#pragma unroll
    for (int mt = 0; mt < 4; ++mt) {
        int row = brow + wm * 64 + mt * 16 + lh * 4;
#pragma unroll
        for (int nt = 0; nt < 4; ++nt) {
            int col = bcol + wn * 64 + nt * 16 + ll;
            float bv = p.bias[col];
#pragma unroll
            for (int q = 0; q < 4; ++q)
                p.C[(size_t)(row + q) * D3 + col] = acc[mt][nt][q] + bv;
        }
    }
}

// ---------------------------------------------------------------------------
// GRU recurrences, persistent-register-weight MFMA (R8 form — plateau).
// ---------------------------------------------------------------------------
#define HSTRIDE 576
#define HBUF    (4 * HSTRIDE)

__global__ __launch_bounds__(512, 2) void k_gru(const float* __restrict__ ef_x,
                                                const float* __restrict__ eb_x,
                                                const float* __restrict__ d_x,
                                                const float* __restrict__ ef_whh, const float* __restrict__ ef_bhh,
                                                const float* __restrict__ eb_whh, const float* __restrict__ eb_bhh,
                                                const float* __restrict__ d_whh, const float* __restrict__ d_bhh,
                                                float* __restrict__ enc_out,
                                                float* __restrict__ dec_out) {
    __shared__ __align__(16) char hb[2 * HBUF];

    int tid = threadIdx.x;
    int dir = blockIdx.x;
    const float *xw, *Whh, *bhh;
    int L;
    if (dir == 0)      { xw = ef_x; Whh = ef_whh; bhh = ef_bhh; L = SS; }
    else if (dir == 1) { xw = eb_x; Whh = eb_whh; bhh = eb_bhh; L = SS; }
    else               { xw = d_x;  Whh = d_whh;  bhh = d_bhh;  L = TT; }

    const int wv = tid >> 6;
    const int lane = tid & 63;
    const int jj = lane & 15;
    const int hi = lane >> 4;
    const int b = hi;

    if (tid < 288) {
        f32x4 z = {0.f, 0.f, 0.f, 0.f};
        *(f32x4*)(hb + tid * 16) = z;
    }

    s16x8 wf[3][2][8];
#pragma unroll
    for (int g = 0; g < 3; ++g)
#pragma unroll
        for (int t = 0; t < 2; ++t) {
            const int nrow = g * 256 + wv * 32 + t * 16 + jj;
            const float* wp = Whh + (size_t)nrow * 256 + hi * 8;
#pragma unroll
            for (int sk = 0; sk < 8; ++sk) {
                float4 w0 = *(const float4*)(wp + sk * 32);
                float4 w1 = *(const float4*)(wp + sk * 32 + 4);
                s16x8 v;
                v[0] = f2bf(w0.x); v[1] = f2bf(w0.y); v[2] = f2bf(w0.z); v[3] = f2bf(w0.w);
                v[4] = f2bf(w1.x); v[5] = f2bf(w1.y); v[6] = f2bf(w1.z); v[7] = f2bf(w1.w);
                wf[g][t][sk] = v;
            }
        }

    const int j0 = wv * 32 + jj, j1 = j0 + 16;
    const float br0 = bhh[j0], bz0 = bhh[256 + j0], bn0 = bhh[512 + j0];
    const float br1 = bhh[j1], bz1 = bhh[256 + j1], bn1 = bhh[512 + j1];

    const int arow = jj >> 2;
    const int abase = arow * HSTRIDE + hi * 16;
    const int wo0 = b * HSTRIDE + 2 * j0;
    const int wo1 = b * HSTRIDE + 2 * j1;

    const int s0 = (dir == 1) ? (L - 1) : 0;
    const int sst = (dir == 1) ? -1 : 1;
    const float* xq = xw + ((size_t)b * L + s0) * D3 + j0;
    float* op;
    int ostride;
    if (dir == 2) { op = dec_out + ((size_t)b * TT + s0) * DIM + j0; ostride = sst * DIM; }
    else          { op = enc_out + ((size_t)b * SS + s0) * D2 + (dir == 1 ? DIM : 0) + j0; ostride = sst * D2; }
    const int xstride = sst * D3;

    float c0 = xq[0], c1 = xq[256], c2 = xq[512], c3 = xq[16], c4 = xq[272], c5 = xq[528];

    float h0 = 0.f, h1 = 0.f;
    int cur = 0;
    __syncthreads();

    for (int st = 0; st < L; ++st) {
        xq += xstride;
        float n0 = xq[0], n1 = xq[256], n2 = xq[512], n3 = xq[16], n4 = xq[272], n5 = xq[528];

        const char* hcur = hb + cur * HBUF;
        f32x4 a00 = {0.f, 0.f, 0.f, 0.f}, a01 = a00, a10 = a00, a11 = a00, a20 = a00, a21 = a00;
#pragma unroll
        for (int sk = 0; sk < 8; ++sk) {
            s16x8 af = *(const s16x8*)(hcur + abase + 64 * sk);
            a00 = __builtin_amdgcn_mfma_f32_16x16x32_bf16(af, wf[0][0][sk], a00, 0, 0, 0);
            a01 = __builtin_amdgcn_mfma_f32_16x16x32_bf16(af, wf[0][1][sk], a01, 0, 0, 0);
            a10 = __builtin_amdgcn_mfma_f32_16x16x32_bf16(af, wf[1][0][sk], a10, 0, 0, 0);
            a11 = __builtin_amdgcn_mfma_f32_16x16x32_bf16(af, wf[1][1][sk], a11, 0, 0, 0);
            a20 = __builtin_amdgcn_mfma_f32_16x16x32_bf16(af, wf[2][0][sk], a20, 0, 0, 0);
            a21 = __builtin_amdgcn_mfma_f32_16x16x32_bf16(af, wf[2][1][sk], a21, 0, 0, 0);
        }

        float r0 = sigmoidf_(c0 + a00[0] + br0);
        float z0 = sigmoidf_(c1 + a10[0] + bz0);
        float nn0 = tanhf_(c2 + r0 * (a20[0] + bn0));
        h0 = (1.f - z0) * nn0 + z0 * h0;
        float r1 = sigmoidf_(c3 + a01[0] + br1);
        float z1 = sigmoidf_(c4 + a11[0] + bz1);
        float nn1 = tanhf_(c5 + r1 * (a21[0] + bn1));
        h1 = (1.f - z1) * nn1 + z1 * h1;

        char* hnxt = hb + (cur ^ 1) * HBUF;
        *(short*)(hnxt + wo0) = f2bf(h0);
        *(short*)(hnxt + wo1) = f2bf(h1);
        op[0] = h0;
        op[16] = h1;
        BAR_LGKM();

        cur ^= 1;
        c0 = n0; c1 = n1; c2 = n2; c3 = n3; c4 = n4; c5 = n5;
        op += ostride;
    }
}

// ---------------------------------------------------------------------------
// Attention: one block per (b,t) row, 512 threads.
// ---------------------------------------------------------------------------
__global__ __launch_bounds__(512) void k_attn(const float* __restrict__ Qb,
                                              const float* __restrict__ Kb,
                                              const float* __restrict__ enc_out,
                                              const float* __restrict__ dec_out,
                                              const float* __restrict__ Wgate,
                                              const float* __restrict__ bgate,
                                              float* __restrict__ probs,
                                              short* __restrict__ cmb,
                                              float* __restrict__ gate) {
    __shared__ float q[DIM];
    __shared__ float sc[SS];
    __shared__ float red[512];
    __shared__ float par[2][2][DIM];
    int row = blockIdx.x;
    int b = row >> 8;
    int tid = threadIdx.x;

    if (tid < DIM) q[tid] = Qb[(size_t)row * DIM + tid];
    __syncthreads();

    const float scale = 0.0625f;
    {
        const float* kr = Kb + ((size_t)b * SS + tid) * DIM;
        float acc = 0.0f;
        for (int k = 0; k < DIM; k += 4) {
            float4 k4 = *(const float4*)&kr[k];
            acc += k4.x * q[k] + k4.y * q[k + 1] + k4.z * q[k + 2] + k4.w * q[k + 3];
        }
        sc[tid] = acc * scale;
    }
    __syncthreads();

    red[tid] = sc[tid];
    __syncthreads();
    for (int o = 256; o > 0; o >>= 1) {
        if (tid < o) red[tid] = fmaxf(red[tid], red[tid + o]);
        __syncthreads();
    }
    float m = red[0];
    __syncthreads();

    float e0 = __expf(sc[tid] - m);
    sc[tid] = e0;
    red[tid] = e0;
    __syncthreads();
    for (int o = 256; o > 0; o >>= 1) {
        if (tid < o) red[tid] += red[tid + o];
        __syncthreads();
    }
    float inv = rcp_(red[0]);
    __syncthreads();

    sc[tid] *= inv;
    probs[(size_t)row * SS + tid] = sc[tid];
    __syncthreads();

    {
        int d = tid & 255, sh = tid >> 8;
        float accf = 0.0f, accb = 0.0f;
        const float* ep = enc_out + ((size_t)b * SS + sh * 256) * D2 + d;
        const float* pp = &sc[sh * 256];
        for (int s = 0; s < 256; s++) {
            float p = pp[s];
            accf += p * ep[(size_t)s * D2];
            accb += p * ep[(size_t)s * D2 + DIM];
        }
        par[sh][0][d] = accf;
        par[sh][1][d] = accb;
    }
    __syncthreads();

    if (tid < DIM) {
        float af = par[0][0][tid] + par[1][0][tid];
        float ab = par[0][1][tid] + par[1][1][tid];
        float dv = dec_out[(size_t)row * DIM + tid];
        cmb[(size_t)row * D3 + tid] = f2bf(dv);
        cmb[(size_t)row * D3 + DIM + tid] = f2bf(af);
        cmb[(size_t)row * D3 + 2 * DIM + tid] = f2bf(ab);
        red[tid] = dv * Wgate[tid] + af * Wgate[DIM + tid] + ab * Wgate[2 * DIM + tid];
    }
    __syncthreads();
    for (int o = 128; o > 0; o >>= 1) {
        if (tid < o) red[tid] += red[tid + o];
        __syncthreads();
    }
    if (tid == 0) gate[row] = sigmoidf_(red[0] + bgate[0]);
}

// ---------------------------------------------------------------------------
// Generator logits GEMM + fused rowsum. Two B variants: bf16 (pre-converted)
// and f32 (on-the-fly) fallback when ws lacks the 49MB for Wgen_bf.
// ---------------------------------------------------------------------------
__global__ __launch_bounds__(512) void k_gen_bf(const short* __restrict__ A,
                                                const short* __restrict__ Bbf,
                                                const float* __restrict__ bias,
                                                float* __restrict__ C,
                                                float* __restrict__ rowsum) {
    __shared__ __align__(16) short As[256 * 32];
    __shared__ __align__(16) short Bs[128 * 32];
    int tid = threadIdx.x;
    int lane = tid & 63, wv = tid >> 6;
    int wm = wv >> 1, wn = wv & 1;
    int brow = blockIdx.y * 256, bcol = blockIdx.x * 128;
    f32x4 acc[4][4];
#pragma unroll
    for (int i = 0; i < 4; i++)
#pragma unroll
        for (int j = 0; j < 4; j++) acc[i][j] = (f32x4){0.f, 0.f, 0.f, 0.f};

    const int ca0 = tid, ca1 = tid + 512, cb = tid;
    const int ll = lane & 15, lh = lane >> 4;

    for (int k0 = 0; k0 < D3; k0 += 32) {
        s16x8 va0 = *(const s16x8*)&A[(size_t)(brow + (ca0 >> 2)) * D3 + k0 + (ca0 & 3) * 8];
        s16x8 va1 = *(const s16x8*)&A[(size_t)(brow + (ca1 >> 2)) * D3 + k0 + (ca1 & 3) * 8];
        s16x8 vb  = *(const s16x8*)&Bbf[(size_t)(bcol + (cb >> 2)) * D3 + k0 + (cb & 3) * 8];

        __syncthreads();
        *(s16x8*)&As[ca0 * 8] = va0;
        *(s16x8*)&As[ca1 * 8] = va1;
        *(s16x8*)&Bs[cb * 8] = vb;
        __syncthreads();

        s16x8 af[4], bf[4];
#pragma unroll
        for (int mt = 0; mt < 4; ++mt)
            af[mt] = *(const s16x8*)&As[(wm * 64 + mt * 16 + ll) * 32 + lh * 8];
#pragma unroll
        for (int nt = 0; nt < 4; ++nt)
            bf[nt] = *(const s16x8*)&Bs[(wn * 64 + nt * 16 + ll) * 32 + lh * 8];
#pragma unroll
        for (int mt = 0; mt < 4; ++mt)
#pragma unroll
            for (int nt = 0; nt < 4; ++nt)
                acc[mt][nt] = __builtin_amdgcn_mfma_f32_16x16x32_bf16(af[mt], bf[nt], acc[mt][nt], 0, 0, 0);
    }

#pragma unroll
    for (int nt = 0; nt < 4; ++nt) {
        float bv = bias[bcol + wn * 64 + nt * 16 + ll];
#pragma unroll
        for (int mt = 0; mt < 4; ++mt)
#pragma unroll
            for (int q = 0; q < 4; ++q) acc[mt][nt][q] += bv;
    }

#pragma unroll
    for (int mt = 0; mt < 4; ++mt) {
        int row = brow + wm * 64 + mt * 16 + lh * 4;
#pragma unroll
        for (int nt = 0; nt < 4; ++nt) {
            int col = bcol + wn * 64 + nt * 16 + ll;
#pragma unroll
            for (int q = 0; q < 4; ++q)
                C[(size_t)(row + q) * VV + col] = acc[mt][nt][q];
        }
    }

#pragma unroll
    for (int mt = 0; mt < 4; ++mt) {
#pragma unroll
        for (int q = 0; q < 4; ++q) {
            float se = __expf(acc[mt][0][q]) + __expf(acc[mt][1][q]) +
                       __expf(acc[mt][2][q]) + __expf(acc[mt][3][q]);
#pragma unroll
            for (int off = 1; off < 16; off <<= 1)
                se += __shfl_xor(se, off);
            if (ll == 0) {
                int row = brow + wm * 64 + mt * 16 + lh * 4 + q;
                atomicAdd(&rowsum[row], se);
            }
        }
    }
}

__global__ __launch_bounds__(512) void k_gen(const short* __restrict__ A,
                                             const float* __restrict__ Bw,
                                             const float* __restrict__ bias,
                                             float* __restrict__ C,
                                             float* __restrict__ rowsum) {
    __shared__ __align__(16) short As[256 * 32];
    __shared__ __align__(16) short Bs[128 * 32];
    int tid = threadIdx.x;
    int lane = tid & 63, wv = tid >> 6;
    int wm = wv >> 1, wn = wv & 1;
    int brow = blockIdx.y * 256, bcol = blockIdx.x * 128;
    f32x4 acc[4][4];
#pragma unroll
    for (int i = 0; i < 4; i++)
#pragma unroll
        for (int j = 0; j < 4; j++) acc[i][j] = (f32x4){0.f, 0.f, 0.f, 0.f};

    const int ca0 = tid, ca1 = tid + 512, cb = tid;
    const int ll = lane & 15, lh = lane >> 4;

    for (int k0 = 0; k0 < D3; k0 += 32) {
        s16x8 va0 = *(const s16x8*)&A[(size_t)(brow + (ca0 >> 2)) * D3 + k0 + (ca0 & 3) * 8];
        s16x8 va1 = *(const s16x8*)&A[(size_t)(brow + (ca1 >> 2)) * D3 + k0 + (ca1 & 3) * 8];
        const float* bp = &Bw[(size_t)(bcol + (cb >> 2)) * D3 + k0 + (cb & 3) * 8];
        float4 b0 = *(const float4*)bp;
        float4 b1 = *(const float4*)(bp + 4);
        s16x8 vb;
        vb[0] = f2bf(b0.x); vb[1] = f2bf(b0.y); vb[2] = f2bf(b0.z); vb[3] = f2bf(b0.w);
        vb[4] = f2bf(b1.x); vb[5] = f2bf(b1.y); vb[6] = f2bf(b1.z); vb[7] = f2bf(b1.w);

        __syncthreads();
        *(s16x8*)&As[ca0 * 8] = va0;
        *(s16x8*)&As[ca1 * 8] = va1;
        *(s16x8*)&Bs[cb * 8] = vb;
        __syncthreads();

        s16x8 af[4], bf[4];
#pragma unroll
        for (int mt = 0; mt < 4; ++mt)
            af[mt] = *(const s16x8*)&As[(wm * 64 + mt * 16 + ll) * 32 + lh * 8];
#pragma unroll
        for (int nt = 0; nt < 4; ++nt)
            bf[nt] = *(const s16x8*)&Bs[(wn * 64 + nt * 16 + ll) * 32 + lh * 8];
#pragma unroll
        for (int mt = 0; mt < 4; ++mt)
#pragma unroll
            for (int nt = 0; nt < 4; ++nt)
                acc[mt][nt] = __builtin_amdgcn_mfma_f32_16x16x32_bf16(af[mt], bf[nt], acc[mt][nt], 0, 0, 0);
    }

#pragma unroll
    for (int nt = 0; nt < 4; ++nt) {
        float bv = bias[bcol + wn * 64 + nt * 16 + ll];
#pragma unroll
        for (int mt = 0; mt < 4; ++mt)
#pragma unroll
            for (int q = 0; q < 4; ++q) acc[mt][nt][q] += bv;
    }

#pragma unroll
    for (int mt = 0; mt < 4; ++mt) {
        int row = brow + wm * 64 + mt * 16 + lh * 4;
#pragma unroll
        for (int nt = 0; nt < 4; ++nt) {
            int col = bcol + wn * 64 + nt * 16 + ll;
#pragma unroll
            for (int q = 0; q < 4; ++q)
                C[(size_t)(row + q) * VV + col] = acc[mt][nt][q];
        }
    }

#pragma unroll
    for (int mt = 0; mt < 4; ++mt) {
#pragma unroll
        for (int q = 0; q < 4; ++q) {
            float se = __expf(acc[mt][0][q]) + __expf(acc[mt][1][q]) +
                       __expf(acc[mt][2][q]) + __expf(acc[mt][3][q]);
#pragma unroll
            for (int off = 1; off < 16; off <<= 1)
                se += __shfl_xor(se, off);
            if (ll == 0) {
                int row = brow + wm * 64 + mt * 16 + lh * 4 + q;
                atomicAdd(&rowsum[row], se);
            }
        }
    }
}

// ---------------------------------------------------------------------------
// Fused normalize + copy-scatter: one block per row.
// ---------------------------------------------------------------------------
__global__ __launch_bounds__(256) void k_finsc(const int* __restrict__ src,
                                               const float* __restrict__ probs,
                                               const float* __restrict__ gate,
                                               const float* __restrict__ rowsum,
                                               float* __restrict__ out) {
    int row = blockIdx.x;
    int b = row >> 8;
    int tid = threadIdx.x;
    float g = gate[row];
    float inv = g / rowsum[row];
    float* op = out + (size_t)row * VV;

    for (int i = tid; i < VV / 4; i += 256) {
        float4 l = *(const float4*)&op[i * 4];
        l.x = __expf(l.x) * inv;
        l.y = __expf(l.y) * inv;
        l.z = __expf(l.z) * inv;
        l.w = __expf(l.w) * inv;
        *(float4*)&op[i * 4] = l;
    }
    __syncthreads();

    float og = 1.0f - g;
#pragma unroll
    for (int h = 0; h < 2; ++h) {
        int s = tid + h * 256;
        float val = og * probs[(size_t)row * SS + s];
        atomicAdd(&op[src[b * SS + s]], val);
    }
}

// ---------------------------------------------------------------------------
extern "C" void kernel_launch(void* const* d_in, const int* in_sizes, int n_in,
                              void* d_out, int out_size, void* d_ws, size_t ws_size,
                              hipStream_t stream) {
    const int*   src    = (const int*)d_in[0];
    const int*   tgt    = (const int*)d_in[1];
    const float* emb    = (const float*)d_in[2];
    const float* pos    = (const float*)d_in[3];
    const float* ef_wih = (const float*)d_in[4];
    const float* ef_whh = (const float*)d_in[5];
    const float* ef_bih = (const float*)d_in[6];
    const float* ef_bhh = (const float*)d_in[7];
    const float* eb_wih = (const float*)d_in[8];
    const float* eb_whh = (const float*)d_in[9];
    const float* eb_bih = (const float*)d_in[10];
    const float* eb_bhh = (const float*)d_in[11];
    const float* d_wih  = (const float*)d_in[12];
    const float* d_whh  = (const float*)d_in[13];
    const float* d_bih  = (const float*)d_in[14];
    const float* d_bhh  = (const float*)d_in[15];
    const float* Wq     = (const float*)d_in[16];
    const float* Wk     = (const float*)d_in[17];
    const float* Wgen   = (const float*)d_in[18];
    const float* bgen   = (const float*)d_in[19];
    const float* Wgate  = (const float*)d_in[20];
    const float* bgate  = (const float*)d_in[21];
    float* out = (float*)d_out;
    float* ws  = (float*)d_ws;

    float* src_emb  = ws;
    float* tgt_emb  = src_emb + (size_t)BB * SS * DIM;
    float* ef_x     = tgt_emb + (size_t)BB * TT * DIM;
    float* eb_x     = ef_x + (size_t)BB * SS * D3;
    float* d_x      = eb_x + (size_t)BB * SS * D3;
    float* enc_out  = d_x + (size_t)BB * TT * D3;
    float* dec_out  = enc_out + (size_t)BB * SS * D2;
    float* Qb       = dec_out + (size_t)BB * TT * DIM;
    float* Kb       = Qb + (size_t)BB * TT * DIM;
    float* probs    = Kb + (size_t)BB * SS * DIM;
    short* cmb_bf   = (short*)(probs + (size_t)BB * TT * SS);
    float* gate     = (float*)(cmb_bf + (size_t)BB * TT * D3);
    float* rowsum   = gate + 1024;
    short* wgen_bf  = (short*)(rowsum + 1024);
    const bool use_bf = ws_size >= (size_t)((char*)(wgen_bf + (size_t)VV * D3) - (char*)d_ws);

    hipMemsetAsync(rowsum, 0, 1024 * sizeof(float), stream);

    // 1. embeddings
    k_embed<<<(BB * SS * DIM + BB * TT * DIM) / 256, 256, 0, stream>>>(
        src, tgt, emb, pos, src_emb, tgt_emb);

    // 1b. Wgen -> bf16 pre-convert (L3-resident 49MB; halves k_gen B traffic)
    if (use_bf)
        k_cvt<<<(VV * D3 / 8 + 255) / 256, 256, 0, stream>>>(Wgen, wgen_bf, VV * D3 / 8);

    // 2. input projections: bf16 MFMA, on-the-fly operand conversion
    {
        PDesc e0 = {src_emb, ef_wih, ef_bih, ef_x, BB * SS};
        PDesc e1 = {src_emb, eb_wih, eb_bih, eb_x, BB * SS};
        PDesc e2 = {tgt_emb, d_wih, d_bih, d_x, BB * TT};
        k_proj<<<dim3(D3 / 128, BB * SS / 256, 3), 512, 0, stream>>>(e0, e1, e2);
    }

    // 3. the three recurrences
    k_gru<<<3, 512, 0, stream>>>(ef_x, eb_x, d_x, ef_whh, ef_bhh, eb_whh, eb_bhh,
                                 d_whh, d_bhh, enc_out, dec_out);

    // 4. Q/K projections (f32, small)
    {
        GDesc q0 = {dec_out, DIM, Wq, DIM, nullptr, Qb, DIM, BB * TT, DIM};
        GDesc q1 = {enc_out, D2, Wk, D2, nullptr, Kb, DIM, BB * SS, DIM};
        k_gemmb<<<dim3(DIM / BNN, BB * SS / BMM, 2), 256, 0, stream>>>(q0, q1, q1);
    }

    // 5. attention + combined(bf16) + gate
    k_attn<<<BB * TT, 512, 0, stream>>>(Qb, Kb, enc_out, dec_out, Wgate, bgate,
                                        probs, cmb_bf, gate);

    // 6. generator logits + fused rowsum
    if (use_bf)
        k_gen_bf<<<dim3(VV / 128, (BB * TT) / 256), 512, 0, stream>>>(cmb_bf, wgen_bf, bgen, out, rowsum);
    else
        k_gen<<<dim3(VV / 128, (BB * TT) / 256), 512, 0, stream>>>(cmb_bf, Wgen, bgen, out, rowsum);

    // 7. fused normalize + copy-scatter
    k_finsc<<<BB * TT, 256, 0, stream>>>(src, probs, gate, rowsum, out);
}

// Round 10
// 1072.039 us; speedup vs baseline: 1.0826x; 1.0655x over previous
//
#include <hip/hip_runtime.h>
#include <hip/hip_bf16.h>
#include <math.h>

// Problem dims
#define VV   32000
#define DIM  256
#define BB   4
#define SS   512
#define TT   256
#define D2   512
#define D3   768

typedef __attribute__((ext_vector_type(8))) short s16x8;
typedef __attribute__((ext_vector_type(4))) float f32x4;

__device__ __forceinline__ float rcp_(float x) { return __builtin_amdgcn_rcpf(x); }
__device__ __forceinline__ float sigmoidf_(float x) { return rcp_(1.0f + __expf(-x)); }
__device__ __forceinline__ float tanhf_(float x) {
    float t = __expf(-2.0f * x);
    return (1.0f - t) * rcp_(1.0f + t);
}
__device__ __forceinline__ short f2bf(float f) {  // RNE f32->bf16
    unsigned u = __float_as_uint(f);
    u += 0x7FFFu + ((u >> 16) & 1u);
    return (short)(u >> 16);
}

// R4-proven barrier: lgkm-only drain keeps global loads/stores in flight.
#define BAR_LGKM() asm volatile("s_waitcnt lgkmcnt(0)\n\ts_barrier" ::: "memory")

// ---------------------------------------------------------------------------
// Input projections with FUSED embedding: C[M,768] = (emb[tok]+pos) @ W^T + b.
// bf16 MFMA, on-the-fly conversion in staging. Tile 256x128, BK=32, 512 thr.
// ---------------------------------------------------------------------------
struct PDesc {
    const int* tok;      // flattened [B*L]
    const float* Wt;     // [768,256]
    const float* bias;   // [768]
    float* C;            // [M,768]
    int M;
    int lmask;           // L-1 (pow2)
};

__global__ __launch_bounds__(512) void k_proj(const float* __restrict__ emb,
                                              const float* __restrict__ pos,
                                              PDesc p0, PDesc p1, PDesc p2) {
    PDesc p = (blockIdx.z == 0) ? p0 : ((blockIdx.z == 1) ? p1 : p2);
    int brow = blockIdx.y * 256;
    if (brow >= p.M) return;
    int bcol = blockIdx.x * 128;

    __shared__ __align__(16) short As[256 * 32];
    __shared__ __align__(16) short Bs[128 * 32];
    int tid = threadIdx.x;
    int lane = tid & 63, wv = tid >> 6;
    int wm = wv >> 1, wn = wv & 1;
    const int ll = lane & 15, lh = lane >> 4;

    f32x4 acc[4][4];
#pragma unroll
    for (int i = 0; i < 4; i++)
#pragma unroll
        for (int j = 0; j < 4; j++) acc[i][j] = (f32x4){0.f, 0.f, 0.f, 0.f};

    const int ar = tid >> 1, ak = (tid & 1) * 16;
    const int br = tid >> 2, bk = (tid & 3) * 8;
    const int grow = brow + ar;
    const float* erow = emb + (size_t)p.tok[grow] * DIM;
    const float* prow = pos + (size_t)(grow & p.lmask) * DIM;

    for (int k0 = 0; k0 < DIM; k0 += 32) {
        float4 a0 = *(const float4*)(erow + k0 + ak);
        float4 a1 = *(const float4*)(erow + k0 + ak + 4);
        float4 a2 = *(const float4*)(erow + k0 + ak + 8);
        float4 a3 = *(const float4*)(erow + k0 + ak + 12);
        float4 q0 = *(const float4*)(prow + k0 + ak);
        float4 q1 = *(const float4*)(prow + k0 + ak + 4);
        float4 q2 = *(const float4*)(prow + k0 + ak + 8);
        float4 q3 = *(const float4*)(prow + k0 + ak + 12);
        const float* bp = &p.Wt[(size_t)(bcol + br) * DIM + k0 + bk];
        float4 b0 = *(const float4*)bp;
        float4 b1 = *(const float4*)(bp + 4);
        s16x8 va0, va1, vb;
        va0[0] = f2bf(a0.x + q0.x); va0[1] = f2bf(a0.y + q0.y);
        va0[2] = f2bf(a0.z + q0.z); va0[3] = f2bf(a0.w + q0.w);
        va0[4] = f2bf(a1.x + q1.x); va0[5] = f2bf(a1.y + q1.y);
        va0[6] = f2bf(a1.z + q1.z); va0[7] = f2bf(a1.w + q1.w);
        va1[0] = f2bf(a2.x + q2.x); va1[1] = f2bf(a2.y + q2.y);
        va1[2] = f2bf(a2.z + q2.z); va1[3] = f2bf(a2.w + q2.w);
        va1[4] = f2bf(a3.x + q3.x); va1[5] = f2bf(a3.y + q3.y);
        va1[6] = f2bf(a3.z + q3.z); va1[7] = f2bf(a3.w + q3.w);
        vb[0] = f2bf(b0.x); vb[1] = f2bf(b0.y); vb[2] = f2bf(b0.z); vb[3] = f2bf(b0.w);
        vb[4] = f2bf(b1.x); vb[5] = f2bf(b1.y); vb[6] = f2bf(b1.z); vb[7] = f2bf(b1.w);

        __syncthreads();
        *(s16x8*)&As[ar * 32 + ak] = va0;
        *(s16x8*)&As[ar * 32 + ak + 8] = va1;
        *(s16x8*)&Bs[br * 32 + bk] = vb;
        __syncthreads();

        s16x8 af[4], bf[4];
#pragma unroll
        for (int mt = 0; mt < 4; ++mt)
            af[mt] = *(const s16x8*)&As[(wm * 64 + mt * 16 + ll) * 32 + lh * 8];
#pragma unroll
        for (int nt = 0; nt < 4; ++nt)
            bf[nt] = *(const s16x8*)&Bs[(wn * 64 + nt * 16 + ll) * 32 + lh * 8];
#pragma unroll
        for (int mt = 0; mt < 4; ++mt)
#pragma unroll
            for (int nt = 0; nt < 4; ++nt)
                acc[mt][nt] = __builtin_amdgcn_mfma_f32_16x16x32_bf16(af[mt], bf[nt], acc[mt][nt], 0, 0, 0);
    }

#pragma unroll
    for (int mt = 0; mt < 4; ++mt) {
        int row = brow + wm * 64 + mt * 16 + lh * 4;
#pragma unroll
        for (int nt = 0; nt < 4; ++nt) {
            int col = bcol + wn * 64 + nt * 16 + ll;
            float bv = p.bias[col];
#pragma unroll
            for (int q = 0; q < 4; ++q)
                p.C[(size_t)(row + q) * D3 + col] = acc[mt][nt][q] + bv;
        }
    }
}

// ---------------------------------------------------------------------------
// Batched small f32 GEMM (Q/K projections).
// ---------------------------------------------------------------------------
struct GDesc {
    const float* A; int lda;
    const float* Bt; int ldb;
    const float* bias;
    float* C; int ldc;
    int M, N;
};

#define BMM 128
#define BNN 128
#define BKK 8

__global__ __launch_bounds__(256) void k_gemmb(GDesc d0, GDesc d1, GDesc d2) {
    GDesc d = (blockIdx.z == 0) ? d0 : ((blockIdx.z == 1) ? d1 : d2);
    int brow = blockIdx.y * BMM, bcol = blockIdx.x * BNN;
    if (brow >= d.M || bcol >= d.N) return;

    __shared__ float As[BKK][BMM + 4];
    __shared__ float Bs[BKK][BNN + 4];
    const int K = d.lda;
    int tid = threadIdx.x;
    int tx = tid & 15, ty = tid >> 4;
    float acc[8][8];
#pragma unroll
    for (int i = 0; i < 8; i++)
#pragma unroll
        for (int j = 0; j < 8; j++) acc[i][j] = 0.0f;

    int lr = tid >> 1;
    int lk = (tid & 1) * 4;
    for (int k0 = 0; k0 < K; k0 += BKK) {
        float4 a4 = *(const float4*)&d.A[(size_t)(brow + lr) * d.lda + k0 + lk];
        float4 b4 = *(const float4*)&d.Bt[(size_t)(bcol + lr) * d.ldb + k0 + lk];
        As[lk + 0][lr] = a4.x; As[lk + 1][lr] = a4.y; As[lk + 2][lr] = a4.z; As[lk + 3][lr] = a4.w;
        Bs[lk + 0][lr] = b4.x; Bs[lk + 1][lr] = b4.y; Bs[lk + 2][lr] = b4.z; Bs[lk + 3][lr] = b4.w;
        __syncthreads();
#pragma unroll
        for (int kk = 0; kk < BKK; kk++) {
            float4 a0 = *(const float4*)&As[kk][ty * 8];
            float4 a1 = *(const float4*)&As[kk][ty * 8 + 4];
            float4 b0 = *(const float4*)&Bs[kk][tx * 8];
            float4 b1 = *(const float4*)&Bs[kk][tx * 8 + 4];
            float av[8] = {a0.x, a0.y, a0.z, a0.w, a1.x, a1.y, a1.z, a1.w};
            float bv[8] = {b0.x, b0.y, b0.z, b0.w, b1.x, b1.y, b1.z, b1.w};
#pragma unroll
            for (int i = 0; i < 8; i++)
#pragma unroll
                for (int j = 0; j < 8; j++) acc[i][j] += av[i] * bv[j];
        }
        __syncthreads();
    }

#pragma unroll
    for (int i = 0; i < 8; i++) {
        size_t row = brow + ty * 8 + i;
        float4 c0 = make_float4(acc[i][0], acc[i][1], acc[i][2], acc[i][3]);
        float4 c1 = make_float4(acc[i][4], acc[i][5], acc[i][6], acc[i][7]);
        *(float4*)&d.C[row * d.ldc + bcol + tx * 8] = c0;
        *(float4*)&d.C[row * d.ldc + bcol + tx * 8 + 4] = c1;
    }
}

// ---------------------------------------------------------------------------
// GRU recurrences + hidden work on the 253 idle CUs.
// Blocks 0..2: recurrence (1024 thr = 16 waves, 4/SIMD: doubled latency-hiding
// pool vs R9's 2/SIMD; each wave owns 16 cols, wf = 24 frags = 96 VGPR).
// Blocks >=3: Wgen f32->bf16 conversion + rowsum zeroing (drain in ~40us under
// the 705us recurrence; cvt was 40us of SERIAL wall time as its own kernel).
// ---------------------------------------------------------------------------
#define HSTRIDE 576
#define HBUF    (4 * HSTRIDE)
#define NCVT8   ((size_t)VV * D3 / 8)

__global__ __launch_bounds__(1024) void k_gru(const float* __restrict__ ef_x,
                                              const float* __restrict__ eb_x,
                                              const float* __restrict__ d_x,
                                              const float* __restrict__ ef_whh, const float* __restrict__ ef_bhh,
                                              const float* __restrict__ eb_whh, const float* __restrict__ eb_bhh,
                                              const float* __restrict__ d_whh, const float* __restrict__ d_bhh,
                                              float* __restrict__ enc_out,
                                              float* __restrict__ dec_out,
                                              const float* __restrict__ wgen,
                                              short* __restrict__ wgen_bf,
                                              float* __restrict__ rowsum,
                                              int do_cvt) {
    int tid = threadIdx.x;
    int bid = blockIdx.x;

    if (bid >= 3) {   // ---- fused side-work on otherwise-idle CUs ----
        int cb = bid - 3;
        if (cb == 0) rowsum[tid] = 0.0f;
        if (do_cvt) {
            size_t i = (size_t)cb * 1024 + tid;
            if (i < NCVT8) {
                const float4* p = (const float4*)(wgen + i * 8);
                float4 a = p[0], b4 = p[1];
                s16x8 v;
                v[0] = f2bf(a.x); v[1] = f2bf(a.y); v[2] = f2bf(a.z); v[3] = f2bf(a.w);
                v[4] = f2bf(b4.x); v[5] = f2bf(b4.y); v[6] = f2bf(b4.z); v[7] = f2bf(b4.w);
                *(s16x8*)(wgen_bf + i * 8) = v;
            }
        }
        return;
    }

    __shared__ __align__(16) char hb[2 * HBUF];
    int dir = bid;
    const float *xw, *Whh, *bhh;
    int L;
    if (dir == 0)      { xw = ef_x; Whh = ef_whh; bhh = ef_bhh; L = SS; }
    else if (dir == 1) { xw = eb_x; Whh = eb_whh; bhh = eb_bhh; L = SS; }
    else               { xw = d_x;  Whh = d_whh;  bhh = d_bhh;  L = TT; }

    const int wv = tid >> 6;       // wave 0..15, owns cols [16wv, 16wv+16)
    const int lane = tid & 63;
    const int jj = lane & 15;
    const int hi = lane >> 4;
    const int b = hi;

    if (tid < 288) {
        f32x4 z = {0.f, 0.f, 0.f, 0.f};
        *(f32x4*)(hb + tid * 16) = z;
    }

    // persistent B-fragments wf[gate][kslice] (one 16-col tile per wave)
    s16x8 wf[3][8];
#pragma unroll
    for (int g = 0; g < 3; ++g) {
        const int nrow = g * 256 + wv * 16 + jj;
        const float* wp = Whh + (size_t)nrow * 256 + hi * 8;
#pragma unroll
        for (int sk = 0; sk < 8; ++sk) {
            float4 w0 = *(const float4*)(wp + sk * 32);
            float4 w1 = *(const float4*)(wp + sk * 32 + 4);
            s16x8 v;
            v[0] = f2bf(w0.x); v[1] = f2bf(w0.y); v[2] = f2bf(w0.z); v[3] = f2bf(w0.w);
            v[4] = f2bf(w1.x); v[5] = f2bf(w1.y); v[6] = f2bf(w1.z); v[7] = f2bf(w1.w);
            wf[g][sk] = v;
        }
    }

    const int j0 = wv * 16 + jj;
    const float br0 = bhh[j0], bz0 = bhh[256 + j0], bn0 = bhh[512 + j0];

    const int arow = jj >> 2;
    const int abase = arow * HSTRIDE + hi * 16;
    const int wo0 = b * HSTRIDE + 2 * j0;

    const int s0 = (dir == 1) ? (L - 1) : 0;
    const int sst = (dir == 1) ? -1 : 1;
    const float* xq = xw + ((size_t)b * L + s0) * D3 + j0;
    float* op;
    int ostride;
    if (dir == 2) { op = dec_out + ((size_t)b * TT + s0) * DIM + j0; ostride = sst * DIM; }
    else          { op = enc_out + ((size_t)b * SS + s0) * D2 + (dir == 1 ? DIM : 0) + j0; ostride = sst * D2; }
    const int xstride = sst * D3;

    float c0 = xq[0], c1 = xq[256], c2 = xq[512];

    float h0 = 0.f;
    int cur = 0;
    __syncthreads();

    for (int st = 0; st < L; ++st) {
        xq += xstride;
        float n0 = xq[0], n1 = xq[256], n2 = xq[512];

        const char* hcur = hb + cur * HBUF;
        f32x4 a00 = {0.f, 0.f, 0.f, 0.f}, a10 = a00, a20 = a00;
#pragma unroll
        for (int sk = 0; sk < 8; ++sk) {
            s16x8 af = *(const s16x8*)(hcur + abase + 64 * sk);
            a00 = __builtin_amdgcn_mfma_f32_16x16x32_bf16(af, wf[0][sk], a00, 0, 0, 0);
            a10 = __builtin_amdgcn_mfma_f32_16x16x32_bf16(af, wf[1][sk], a10, 0, 0, 0);
            a20 = __builtin_amdgcn_mfma_f32_16x16x32_bf16(af, wf[2][sk], a20, 0, 0, 0);
        }

        float r0 = sigmoidf_(c0 + a00[0] + br0);
        float z0 = sigmoidf_(c1 + a10[0] + bz0);
        float nn0 = tanhf_(c2 + r0 * (a20[0] + bn0));
        h0 = (1.f - z0) * nn0 + z0 * h0;

        char* hnxt = hb + (cur ^ 1) * HBUF;
        *(short*)(hnxt + wo0) = f2bf(h0);
        op[0] = h0;
        BAR_LGKM();

        cur ^= 1;
        c0 = n0; c1 = n1; c2 = n2;
        op += ostride;
    }
}

// ---------------------------------------------------------------------------
// Attention: one block per (b,t) row, 512 threads.
// ---------------------------------------------------------------------------
__global__ __launch_bounds__(512) void k_attn(const float* __restrict__ Qb,
                                              const float* __restrict__ Kb,
                                              const float* __restrict__ enc_out,
                                              const float* __restrict__ dec_out,
                                              const float* __restrict__ Wgate,
                                              const float* __restrict__ bgate,
                                              float* __restrict__ probs,
                                              short* __restrict__ cmb,
                                              float* __restrict__ gate) {
    __shared__ float q[DIM];
    __shared__ float sc[SS];
    __shared__ float red[512];
    __shared__ float par[2][2][DIM];
    int row = blockIdx.x;
    int b = row >> 8;
    int tid = threadIdx.x;

    if (tid < DIM) q[tid] = Qb[(size_t)row * DIM + tid];
    __syncthreads();

    const float scale = 0.0625f;
    {
        const float* kr = Kb + ((size_t)b * SS + tid) * DIM;
        float acc = 0.0f;
        for (int k = 0; k < DIM; k += 4) {
            float4 k4 = *(const float4*)&kr[k];
            acc += k4.x * q[k] + k4.y * q[k + 1] + k4.z * q[k + 2] + k4.w * q[k + 3];
        }
        sc[tid] = acc * scale;
    }
    __syncthreads();

    red[tid] = sc[tid];
    __syncthreads();
    for (int o = 256; o > 0; o >>= 1) {
        if (tid < o) red[tid] = fmaxf(red[tid], red[tid + o]);
        __syncthreads();
    }
    float m = red[0];
    __syncthreads();

    float e0 = __expf(sc[tid] - m);
    sc[tid] = e0;
    red[tid] = e0;
    __syncthreads();
    for (int o = 256; o > 0; o >>= 1) {
        if (tid < o) red[tid] += red[tid + o];
        __syncthreads();
    }
    float inv = rcp_(red[0]);
    __syncthreads();

    sc[tid] *= inv;
    probs[(size_t)row * SS + tid] = sc[tid];
    __syncthreads();

    {
        int d = tid & 255, sh = tid >> 8;
        float accf = 0.0f, accb = 0.0f;
        const float* ep = enc_out + ((size_t)b * SS + sh * 256) * D2 + d;
        const float* pp = &sc[sh * 256];
        for (int s = 0; s < 256; s++) {
            float p = pp[s];
            accf += p * ep[(size_t)s * D2];
            accb += p * ep[(size_t)s * D2 + DIM];
        }
        par[sh][0][d] = accf;
        par[sh][1][d] = accb;
    }
    __syncthreads();

    if (tid < DIM) {
        float af = par[0][0][tid] + par[1][0][tid];
        float ab = par[0][1][tid] + par[1][1][tid];
        float dv = dec_out[(size_t)row * DIM + tid];
        cmb[(size_t)row * D3 + tid] = f2bf(dv);
        cmb[(size_t)row * D3 + DIM + tid] = f2bf(af);
        cmb[(size_t)row * D3 + 2 * DIM + tid] = f2bf(ab);
        red[tid] = dv * Wgate[tid] + af * Wgate[DIM + tid] + ab * Wgate[2 * DIM + tid];
    }
    __syncthreads();
    for (int o = 128; o > 0; o >>= 1) {
        if (tid < o) red[tid] += red[tid + o];
        __syncthreads();
    }
    if (tid == 0) gate[row] = sigmoidf_(red[0] + bgate[0]);
}

// ---------------------------------------------------------------------------
// Generator logits GEMM + fused rowsum (bf16-B and f32-B variants).
// ---------------------------------------------------------------------------
__global__ __launch_bounds__(512) void k_gen_bf(const short* __restrict__ A,
                                                const short* __restrict__ Bbf,
                                                const float* __restrict__ bias,
                                                float* __restrict__ C,
                                                float* __restrict__ rowsum) {
    __shared__ __align__(16) short As[256 * 32];
    __shared__ __align__(16) short Bs[128 * 32];
    int tid = threadIdx.x;
    int lane = tid & 63, wv = tid >> 6;
    int wm = wv >> 1, wn = wv & 1;
    int brow = blockIdx.y * 256, bcol = blockIdx.x * 128;
    f32x4 acc[4][4];
#pragma unroll
    for (int i = 0; i < 4; i++)
#pragma unroll
        for (int j = 0; j < 4; j++) acc[i][j] = (f32x4){0.f, 0.f, 0.f, 0.f};

    const int ca0 = tid, ca1 = tid + 512, cb = tid;
    const int ll = lane & 15, lh = lane >> 4;

    for (int k0 = 0; k0 < D3; k0 += 32) {
        s16x8 va0 = *(const s16x8*)&A[(size_t)(brow + (ca0 >> 2)) * D3 + k0 + (ca0 & 3) * 8];
        s16x8 va1 = *(const s16x8*)&A[(size_t)(brow + (ca1 >> 2)) * D3 + k0 + (ca1 & 3) * 8];
        s16x8 vb  = *(const s16x8*)&Bbf[(size_t)(bcol + (cb >> 2)) * D3 + k0 + (cb & 3) * 8];

        __syncthreads();
        *(s16x8*)&As[ca0 * 8] = va0;
        *(s16x8*)&As[ca1 * 8] = va1;
        *(s16x8*)&Bs[cb * 8] = vb;
        __syncthreads();

        s16x8 af[4], bf[4];
#pragma unroll
        for (int mt = 0; mt < 4; ++mt)
            af[mt] = *(const s16x8*)&As[(wm * 64 + mt * 16 + ll) * 32 + lh * 8];
#pragma unroll
        for (int nt = 0; nt < 4; ++nt)
            bf[nt] = *(const s16x8*)&Bs[(wn * 64 + nt * 16 + ll) * 32 + lh * 8];
#pragma unroll
        for (int mt = 0; mt < 4; ++mt)
#pragma unroll
            for (int nt = 0; nt < 4; ++nt)
                acc[mt][nt] = __builtin_amdgcn_mfma_f32_16x16x32_bf16(af[mt], bf[nt], acc[mt][nt], 0, 0, 0);
    }

#pragma unroll
    for (int nt = 0; nt < 4; ++nt) {
        float bv = bias[bcol + wn * 64 + nt * 16 + ll];
#pragma unroll
        for (int mt = 0; mt < 4; ++mt)
#pragma unroll
            for (int q = 0; q < 4; ++q) acc[mt][nt][q] += bv;
    }

#pragma unroll
    for (int mt = 0; mt < 4; ++mt) {
        int row = brow + wm * 64 + mt * 16 + lh * 4;
#pragma unroll
        for (int nt = 0; nt < 4; ++nt) {
            int col = bcol + wn * 64 + nt * 16 + ll;
#pragma unroll
            for (int q = 0; q < 4; ++q)
                C[(size_t)(row + q) * VV + col] = acc[mt][nt][q];
        }
    }

#pragma unroll
    for (int mt = 0; mt < 4; ++mt) {
#pragma unroll
        for (int q = 0; q < 4; ++q) {
            float se = __expf(acc[mt][0][q]) + __expf(acc[mt][1][q]) +
                       __expf(acc[mt][2][q]) + __expf(acc[mt][3][q]);
#pragma unroll
            for (int off = 1; off < 16; off <<= 1)
                se += __shfl_xor(se, off);
            if (ll == 0) {
                int row = brow + wm * 64 + mt * 16 + lh * 4 + q;
                atomicAdd(&rowsum[row], se);
            }
        }
    }
}

__global__ __launch_bounds__(512) void k_gen(const short* __restrict__ A,
                                             const float* __restrict__ Bw,
                                             const float* __restrict__ bias,
                                             float* __restrict__ C,
                                             float* __restrict__ rowsum) {
    __shared__ __align__(16) short As[256 * 32];
    __shared__ __align__(16) short Bs[128 * 32];
    int tid = threadIdx.x;
    int lane = tid & 63, wv = tid >> 6;
    int wm = wv >> 1, wn = wv & 1;
    int brow = blockIdx.y * 256, bcol = blockIdx.x * 128;
    f32x4 acc[4][4];
#pragma unroll
    for (int i = 0; i < 4; i++)
#pragma unroll
        for (int j = 0; j < 4; j++) acc[i][j] = (f32x4){0.f, 0.f, 0.f, 0.f};

    const int ca0 = tid, ca1 = tid + 512, cb = tid;
    const int ll = lane & 15, lh = lane >> 4;

    for (int k0 = 0; k0 < D3; k0 += 32) {
        s16x8 va0 = *(const s16x8*)&A[(size_t)(brow + (ca0 >> 2)) * D3 + k0 + (ca0 & 3) * 8];
        s16x8 va1 = *(const s16x8*)&A[(size_t)(brow + (ca1 >> 2)) * D3 + k0 + (ca1 & 3) * 8];
        const float* bp = &Bw[(size_t)(bcol + (cb >> 2)) * D3 + k0 + (cb & 3) * 8];
        float4 b0 = *(const float4*)bp;
        float4 b1 = *(const float4*)(bp + 4);
        s16x8 vb;
        vb[0] = f2bf(b0.x); vb[1] = f2bf(b0.y); vb[2] = f2bf(b0.z); vb[3] = f2bf(b0.w);
        vb[4] = f2bf(b1.x); vb[5] = f2bf(b1.y); vb[6] = f2bf(b1.z); vb[7] = f2bf(b1.w);

        __syncthreads();
        *(s16x8*)&As[ca0 * 8] = va0;
        *(s16x8*)&As[ca1 * 8] = va1;
        *(s16x8*)&Bs[cb * 8] = vb;
        __syncthreads();

        s16x8 af[4], bf[4];
#pragma unroll
        for (int mt = 0; mt < 4; ++mt)
            af[mt] = *(const s16x8*)&As[(wm * 64 + mt * 16 + ll) * 32 + lh * 8];
#pragma unroll
        for (int nt = 0; nt < 4; ++nt)
            bf[nt] = *(const s16x8*)&Bs[(wn * 64 + nt * 16 + ll) * 32 + lh * 8];
#pragma unroll
        for (int mt = 0; mt < 4; ++mt)
#pragma unroll
            for (int nt = 0; nt < 4; ++nt)
                acc[mt][nt] = __builtin_amdgcn_mfma_f32_16x16x32_bf16(af[mt], bf[nt], acc[mt][nt], 0, 0, 0);
    }

#pragma unroll
    for (int nt = 0; nt < 4; ++nt) {
        float bv = bias[bcol + wn * 64 + nt * 16 + ll];
#pragma unroll
        for (int mt = 0; mt < 4; ++mt)
#pragma unroll
            for (int q = 0; q < 4; ++q) acc[mt][nt][q] += bv;
    }

#pragma unroll
    for (int mt = 0; mt < 4; ++mt) {
        int row = brow + wm * 64 + mt * 16 + lh * 4;
#pragma unroll
        for (int nt = 0; nt < 4; ++nt) {
            int col = bcol + wn * 64 + nt * 16 + ll;
#pragma unroll
            for (int q = 0; q < 4; ++q)
                C[(size_t)(row + q) * VV + col] = acc[mt][nt][q];
        }
    }

#pragma unroll
    for (int mt = 0; mt < 4; ++mt) {
#pragma unroll
        for (int q = 0; q < 4; ++q) {
            float se = __expf(acc[mt][0][q]) + __expf(acc[mt][1][q]) +
                       __expf(acc[mt][2][q]) + __expf(acc[mt][3][q]);
#pragma unroll
            for (int off = 1; off < 16; off <<= 1)
                se += __shfl_xor(se, off);
            if (ll == 0) {
                int row = brow + wm * 64 + mt * 16 + lh * 4 + q;
                atomicAdd(&rowsum[row], se);
            }
        }
    }
}

// ---------------------------------------------------------------------------
// Fused normalize + copy-scatter: one block per row.
// ---------------------------------------------------------------------------
__global__ __launch_bounds__(256) void k_finsc(const int* __restrict__ src,
                                               const float* __restrict__ probs,
                                               const float* __restrict__ gate,
                                               const float* __restrict__ rowsum,
                                               float* __restrict__ out) {
    int row = blockIdx.x;
    int b = row >> 8;
    int tid = threadIdx.x;
    float g = gate[row];
    float inv = g / rowsum[row];
    float* op = out + (size_t)row * VV;

    for (int i = tid; i < VV / 4; i += 256) {
        float4 l = *(const float4*)&op[i * 4];
        l.x = __expf(l.x) * inv;
        l.y = __expf(l.y) * inv;
        l.z = __expf(l.z) * inv;
        l.w = __expf(l.w) * inv;
        *(float4*)&op[i * 4] = l;
    }
    __syncthreads();

    float og = 1.0f - g;
#pragma unroll
    for (int h = 0; h < 2; ++h) {
        int s = tid + h * 256;
        float val = og * probs[(size_t)row * SS + s];
        atomicAdd(&op[src[b * SS + s]], val);
    }
}

// ---------------------------------------------------------------------------
extern "C" void kernel_launch(void* const* d_in, const int* in_sizes, int n_in,
                              void* d_out, int out_size, void* d_ws, size_t ws_size,
                              hipStream_t stream) {
    const int*   src    = (const int*)d_in[0];
    const int*   tgt    = (const int*)d_in[1];
    const float* emb    = (const float*)d_in[2];
    const float* pos    = (const float*)d_in[3];
    const float* ef_wih = (const float*)d_in[4];
    const float* ef_whh = (const float*)d_in[5];
    const float* ef_bih = (const float*)d_in[6];
    const float* ef_bhh = (const float*)d_in[7];
    const float* eb_wih = (const float*)d_in[8];
    const float* eb_whh = (const float*)d_in[9];
    const float* eb_bih = (const float*)d_in[10];
    const float* eb_bhh = (const float*)d_in[11];
    const float* d_wih  = (const float*)d_in[12];
    const float* d_whh  = (const float*)d_in[13];
    const float* d_bih  = (const float*)d_in[14];
    const float* d_bhh  = (const float*)d_in[15];
    const float* Wq     = (const float*)d_in[16];
    const float* Wk     = (const float*)d_in[17];
    const float* Wgen   = (const float*)d_in[18];
    const float* bgen   = (const float*)d_in[19];
    const float* Wgate  = (const float*)d_in[20];
    const float* bgate  = (const float*)d_in[21];
    float* out = (float*)d_out;
    float* ws  = (float*)d_ws;

    float* ef_x     = ws;
    float* eb_x     = ef_x + (size_t)BB * SS * D3;
    float* d_x      = eb_x + (size_t)BB * SS * D3;
    float* enc_out  = d_x + (size_t)BB * TT * D3;
    float* dec_out  = enc_out + (size_t)BB * SS * D2;
    float* Qb       = dec_out + (size_t)BB * TT * DIM;
    float* Kb       = Qb + (size_t)BB * TT * DIM;
    float* probs    = Kb + (size_t)BB * SS * DIM;
    short* cmb_bf   = (short*)(probs + (size_t)BB * TT * SS);
    float* gate     = (float*)(cmb_bf + (size_t)BB * TT * D3);
    float* rowsum   = gate + 1024;
    short* wgen_bf  = (short*)(rowsum + 1024);
    const bool use_bf = ws_size >= (size_t)((char*)(wgen_bf + (size_t)VV * D3) - (char*)d_ws);

    // 1. input projections with fused embedding (bf16 MFMA)
    {
        PDesc e0 = {src, ef_wih, ef_bih, ef_x, BB * SS, SS - 1};
        PDesc e1 = {src, eb_wih, eb_bih, eb_x, BB * SS, SS - 1};
        PDesc e2 = {tgt, d_wih, d_bih, d_x, BB * TT, TT - 1};
        k_proj<<<dim3(D3 / 128, BB * SS / 256, 3), 512, 0, stream>>>(emb, pos, e0, e1, e2);
    }

    // 2. recurrences (blocks 0-2) + Wgen cvt + rowsum zero on idle CUs
    {
        int ncvtb = (int)((NCVT8 + 1023) / 1024);
        k_gru<<<3 + ncvtb, 1024, 0, stream>>>(ef_x, eb_x, d_x,
                                              ef_whh, ef_bhh, eb_whh, eb_bhh, d_whh, d_bhh,
                                              enc_out, dec_out,
                                              Wgen, wgen_bf, rowsum, use_bf ? 1 : 0);
    }

    // 3. Q/K projections (f32, small)
    {
        GDesc q0 = {dec_out, DIM, Wq, DIM, nullptr, Qb, DIM, BB * TT, DIM};
        GDesc q1 = {enc_out, D2, Wk, D2, nullptr, Kb, DIM, BB * SS, DIM};
        k_gemmb<<<dim3(DIM / BNN, BB * SS / BMM, 2), 256, 0, stream>>>(q0, q1, q1);
    }

    // 4. attention + combined(bf16) + gate
    k_attn<<<BB * TT, 512, 0, stream>>>(Qb, Kb, enc_out, dec_out, Wgate, bgate,
                                        probs, cmb_bf, gate);

    // 5. generator logits + fused rowsum
    if (use_bf)
        k_gen_bf<<<dim3(VV / 128, (BB * TT) / 256), 512, 0, stream>>>(cmb_bf, wgen_bf, bgen, out, rowsum);
    else
        k_gen<<<dim3(VV / 128, (BB * TT) / 256), 512, 0, stream>>>(cmb_bf, Wgen, bgen, out, rowsum);

    // 6. fused normalize + copy-scatter
    k_finsc<<<BB * TT, 256, 0, stream>>>(src, probs, gate, rowsum, out);
}